// Round 14
// baseline (104.428 us; speedup 1.0000x reference)
//
#include <hip/hip_runtime.h>
#include <hip/hip_bf16.h>
#include <math.h>

// Problem constants (B=1)
#define TT   512
#define CEMB 768
#define NH   12
#define NKV  6
#define HD   64
#define KVC  (NKV*HD)   // 384

typedef short short8 __attribute__((ext_vector_type(8)));
typedef float floatx4 __attribute__((ext_vector_type(4)));
typedef float floatx2 __attribute__((ext_vector_type(2)));

// fp32 pair -> packed bf16 (round-to-nearest via HW packed convert)
__device__ __forceinline__ unsigned pack_bf16(float lo, float hi){
  __hip_bfloat162 h = __float22bfloat162_rn(make_float2(lo, hi));
  return *reinterpret_cast<unsigned*>(&h);
}
__device__ __forceinline__ unsigned short bf16_rn(float f){
  unsigned u = __float_as_uint(f);
  u += 0x7FFFu + ((u>>16)&1u);
  return (unsigned short)(u>>16);
}
__device__ __forceinline__ float bf16_to_f32(unsigned short u){
  return __uint_as_float(((unsigned)u) << 16);
}

// ============================================================================
// K1: QKV GEMM via bf16 MFMA (2-deep reg prefetch) + RoPE/RMS epilogue.
// Grid x: 0..191 = gemm tiles, 192..227 = Wp fragment-pack blocks
// (coalesced one-thread-one-fragment-row form, R11-proven).
// ============================================================================
__global__ void __launch_bounds__(256) gemm_qkv_mfma(
    const float* __restrict__ X,
    const float* __restrict__ Wq, const float* __restrict__ Wk, const float* __restrict__ Wv,
    const float* __restrict__ Wp,
    const float* __restrict__ cosb, const float* __restrict__ sinb,
    float* __restrict__ q, float* __restrict__ k, float* __restrict__ v,
    unsigned short* __restrict__ WpF){
  int bx = blockIdx.x;
  if (bx >= 192){
    int t0 = (bx-192)*256 + threadIdx.x;           // 0..9215
    for(int g=0; g<8; ++g){
      int u  = g*9216 + t0;                        // 0..73727: frag row (ct,ks,qq,r)
      int r  = u & 15;
      int v2 = u >> 4;            // (ct*24+ks)*4 + qq
      int qq = v2 & 3;
      int v3 = v2 >> 2;           // ct*24 + ks
      int ks = v3 % 24;
      int ct = v3 / 24;
      int n  = ct*16 + r;
      int kb = ks*32 + qq*8;
      unsigned p0 = pack_bf16(Wp[(size_t)(kb  )*CEMB + n], Wp[(size_t)(kb+1)*CEMB + n]);
      unsigned p1 = pack_bf16(Wp[(size_t)(kb+2)*CEMB + n], Wp[(size_t)(kb+3)*CEMB + n]);
      unsigned p2 = pack_bf16(Wp[(size_t)(kb+4)*CEMB + n], Wp[(size_t)(kb+5)*CEMB + n]);
      unsigned p3 = pack_bf16(Wp[(size_t)(kb+6)*CEMB + n], Wp[(size_t)(kb+7)*CEMB + n]);
      *(uint4*)&WpF[(size_t)u*8] = make_uint4(p0,p1,p2,p3);
    }
    return;
  }
  int mt = bx / 24, nt = bx % 24;
  const float* W; int ldb, bcol;
  if (nt < 12)      { W = Wq; ldb = CEMB; bcol = nt*64; }
  else if (nt < 18) { W = Wk; ldb = KVC;  bcol = (nt-12)*64; }
  else              { W = Wv; ldb = KVC;  bcol = (nt-18)*64; }

  __shared__ __align__(16) unsigned short Al[2][64][40];
  __shared__ __align__(16) unsigned short Bl[2][64][40];

  int tid = threadIdx.x;
  int am  = tid>>2,  akg = (tid&3)*8;
  int bkp = tid>>4,  bn4 = (tid&15)*4;
  int w = tid>>6, lane = tid&63, qq = lane>>4, r = lane&15;

  floatx4 acc[4];
  #pragma unroll
  for(int c=0;c<4;c++) acc[c] = (floatx4){0.f,0.f,0.f,0.f};

  const float* Ap = X + (size_t)(mt*64 + am)*CEMB + akg;
  const float* Bp = W + (size_t)(2*bkp)*ldb + bcol + bn4;

  float4 a00 = *(const float4*)(Ap);
  float4 a01 = *(const float4*)(Ap + 4);
  float4 b00 = *(const float4*)(Bp);
  float4 b01 = *(const float4*)(Bp + ldb);
  float4 a10 = *(const float4*)(Ap + 32);
  float4 a11 = *(const float4*)(Ap + 36);
  float4 b10 = *(const float4*)(Bp + (size_t)32*ldb);
  float4 b11 = *(const float4*)(Bp + (size_t)33*ldb);

  auto step = [&](int k0, float4& A0, float4& A1, float4& B0, float4& B1,
                  int bufc) {
    unsigned p0 = pack_bf16(A0.x,A0.y), p1 = pack_bf16(A0.z,A0.w);
    unsigned p2 = pack_bf16(A1.x,A1.y), p3 = pack_bf16(A1.z,A1.w);
    *(uint4*)&Al[bufc][am][akg] = make_uint4(p0,p1,p2,p3);
    #pragma unroll
    for(int i=0;i<4;i++)
      *(unsigned*)&Bl[bufc][bn4+i][2*bkp] = pack_bf16((&B0.x)[i], (&B1.x)[i]);
    if (k0 + 64 < CEMB){                 // prefetch 2 steps ahead
      A0 = *(const float4*)(Ap + k0+64);
      A1 = *(const float4*)(Ap + k0+68);
      B0 = *(const float4*)(Bp + (size_t)(k0+64)*ldb);
      B1 = *(const float4*)(Bp + (size_t)(k0+65)*ldb);
    }
    __syncthreads();
    short8 af = *(short8*)&Al[bufc][w*16 + r][qq*8];
    #pragma unroll
    for(int c=0;c<4;c++){
      short8 bfr = *(short8*)&Bl[bufc][c*16 + r][qq*8];
      acc[c] = __builtin_amdgcn_mfma_f32_16x16x32_bf16(af, bfr, acc[c], 0,0,0);
    }
  };

  for(int k0=0; k0<CEMB; k0+=64){
    step(k0,    a00,a01,b00,b01, 0);
    step(k0+32, a10,a11,b10,b11, 1);
  }

  // epilogue: RoPE pairs d<->d+32 = acc c<->c+2 (same lane); RMS over 16 lanes.
  #pragma unroll
  for(int reg=0; reg<4; ++reg){
    int t = mt*64 + w*16 + qq*4 + reg;
    if (nt < 18){
      float cs0 = cosb[t*32 + r],      sn0 = sinb[t*32 + r];
      float cs1 = cosb[t*32 + 16 + r], sn1 = sinb[t*32 + 16 + r];
      float x0 = acc[0][reg], x1 = acc[1][reg], x2 = acc[2][reg], x3 = acc[3][reg];
      float n0 = x0*cs0 - x2*sn0;
      float n1 = x1*cs1 - x3*sn1;
      float n2 = x2*cs0 + x0*sn0;
      float n3 = x3*cs1 + x1*sn1;
      float ss = n0*n0 + n1*n1 + n2*n2 + n3*n3;
      ss += __shfl_xor(ss,1); ss += __shfl_xor(ss,2);
      ss += __shfl_xor(ss,4); ss += __shfl_xor(ss,8);
      float sc = rsqrtf(ss*(1.0f/64.0f) + 1e-6f);
      float* dst = (nt < 12) ? (q + (size_t)t*CEMB + nt*64)
                             : (k + (size_t)t*KVC + (nt-12)*64);
      dst[r]    = n0*sc; dst[16+r] = n1*sc;
      dst[32+r] = n2*sc; dst[48+r] = n3*sc;
    } else {
      float* dst = v + (size_t)t*KVC + (nt-18)*64;
      dst[r]    = acc[0][reg]; dst[16+r] = acc[1][reg];
      dst[32+r] = acc[2][reg]; dst[48+r] = acc[3][reg];
    }
  }
}

// ============================================================================
// K2: tropical attention — R8/R11-proven structure (256 thr / 4 rows per
// thread QK with f32 Q/K in LDS, XCD swizzle, __launch_bounds__(256,3),
// unroll-4 dg loop, MFMA PV with bf16 P [row][72] / V^T [n][72]).
// This round (QK inner loop only): the 4 scalar q+k adds per (r,c,dg)
// cell become 2 v_pk_add_f32 (floatx2); max lattice unchanged (clang fuses
// the fmaxf chain to v_max3). Same adds, same maxes => bit-identical s.
// Register footprint unchanged (same float count, split into pairs).
// ============================================================================
__global__ void __launch_bounds__(256, 3) attn_tile(const float* __restrict__ qn,
    const float* __restrict__ kn, const float* __restrict__ vr,
    unsigned short* __restrict__ part_acc, float2* __restrict__ part_ml){
  __shared__ float QPsh[64*68];                          // Q f32 (QK phase)
  __shared__ float Ksh[64*64];                           // K f32, XOR-swizzled
  __shared__ __align__(16) unsigned short VT[64*72];     // V^T bf16 [n][k]
  __shared__ __align__(16) unsigned short Pl[64*72];     // P bf16 [row][k]

  // bijective XCD swizzle: bid%8 = resident XCD (dispatch round-robin);
  // give each XCD a contiguous run of 54 linear tiles.
  int bid = blockIdx.x;                 // 0..431
  int lin = (bid & 7)*54 + (bid >> 3);  // bijection on [0,432)
  int h   = lin / 36;
  int idx = lin % 36;
  int qt = 0, rem = idx;
  while (rem > qt){ rem -= (qt+1); ++qt; }
  int ct = rem;                  // 0..qt
  int t0 = ct*64;

  int kvh  = h >> 1;
  int w    = threadIdx.x >> 6;
  int lane = threadIdx.x & 63;
  int lg   = lane >> 4;
  int lc   = lane & 15;

  // stage Q (f32, stride 68) + K (f32, XOR-swizzled cols)
  #pragma unroll
  for(int sub=0; sub<4; ++sub){
    int rr = w*16 + sub*4 + lg;
    int sw = ((lc ^ (rr>>2)) & 15)*4;
    *(float4*)&QPsh[rr*68 + lc*4] =
      *(const float4*)&qn[(size_t)(qt*64+rr)*CEMB + h*HD + lc*4];
    *(float4*)&Ksh[rr*64 + sw] =
      *(const float4*)&kn[(size_t)(t0+rr)*KVC + kvh*HD + lc*4];
  }
  // stage V transposed as bf16: VT[n][k], pack k-pairs (K1 B-staging idiom)
  {
    int kp = threadIdx.x >> 4;          // k-pair base 0..15
    int n4 = (threadIdx.x & 15)*4;
    #pragma unroll
    for(int half=0; half<2; ++half){
      int kk = (kp + half*16)*2;        // 0..62 even
      float4 v0 = *(const float4*)&vr[(size_t)(t0+kk  )*KVC + kvh*HD + n4];
      float4 v1 = *(const float4*)&vr[(size_t)(t0+kk+1)*KVC + kvh*HD + n4];
      #pragma unroll
      for(int i=0;i<4;i++)
        *(unsigned*)&VT[(n4+i)*72 + kk] = pack_bf16((&v0.x)[i], (&v1.x)[i]);
    }
  }
  __syncthreads();

  float s[4][4];
  #pragma unroll
  for(int r=0;r<4;r++)
    #pragma unroll
    for(int c=0;c<4;c++) s[r][c] = -INFINITY;

  #pragma unroll 4
  for(int dg=0; dg<16; ++dg){
    floatx2 ka[4], kb[4], qa[4], qb[4];
    int ksw = ((dg ^ lc)&15)*4;
    #pragma unroll
    for(int c=0;c<4;c++){
      float4 kv = *(const float4*)&Ksh[(lc*4+c)*64 + ksw];
      ka[c] = (floatx2){kv.x, kv.y};
      kb[c] = (floatx2){kv.z, kv.w};
    }
    #pragma unroll
    for(int r=0;r<4;r++){
      float4 qv = *(const float4*)&QPsh[(w*16+lg*4+r)*68 + dg*4];
      qa[r] = (floatx2){qv.x, qv.y};
      qb[r] = (floatx2){qv.z, qv.w};
    }
    #pragma unroll
    for(int r=0;r<4;r++)
      #pragma unroll
      for(int c=0;c<4;c++){
        floatx2 sa = qa[r] + ka[c];          // v_pk_add_f32
        floatx2 sb = qb[r] + kb[c];          // v_pk_add_f32
        s[r][c] = fmaxf(s[r][c],
                  fmaxf(fmaxf(sa.x, sa.y), fmaxf(sb.x, sb.y)));
      }
  }

  float mrow[4], lrow[4];
  #pragma unroll
  for(int r=0;r<4;r++){
    int i = qt*64 + w*16 + lg*4 + r;
    #pragma unroll
    for(int c=0;c<4;c++)
      if (t0 + lc*4 + c > i) s[r][c] = -INFINITY;   // causal mask
    float mt = fmaxf(fmaxf(s[r][0],s[r][1]), fmaxf(s[r][2],s[r][3]));
    mt = fmaxf(mt, __shfl_xor(mt,1));
    mt = fmaxf(mt, __shfl_xor(mt,2));
    mt = fmaxf(mt, __shfl_xor(mt,4));
    mt = fmaxf(mt, __shfl_xor(mt,8));
    float p0 = __expf(s[r][0]-mt), p1 = __expf(s[r][1]-mt);
    float p2 = __expf(s[r][2]-mt), p3 = __expf(s[r][3]-mt);
    float ps = p0+p1+p2+p3;
    ps += __shfl_xor(ps,1); ps += __shfl_xor(ps,2);
    ps += __shfl_xor(ps,4); ps += __shfl_xor(ps,8);
    mrow[r] = mt; lrow[r] = ps;
    int row = w*16 + lg*4 + r;
    *(unsigned*)&Pl[row*72 + lc*4]     = pack_bf16(p0,p1);
    *(unsigned*)&Pl[row*72 + lc*4 + 2] = pack_bf16(p2,p3);
    if (lc == 0) part_ml[(h*TT + i)*8 + ct] = make_float2(mrow[r], lrow[r]);
  }
  __builtin_amdgcn_wave_barrier();   // DS in-order per wave; P rows wave-private

  // PV via MFMA: wave w computes output rows w*16..w*16+15, all 64 cols.
  {
    int r_ = lane & 15, qq = lane >> 4;
    floatx4 pacc[4];
    #pragma unroll
    for(int c=0;c<4;c++) pacc[c] = (floatx4){0.f,0.f,0.f,0.f};

    short8 af0 = *(const short8*)&Pl[(w*16+r_)*72 + qq*8];
    short8 af1 = *(const short8*)&Pl[(w*16+r_)*72 + 32 + qq*8];
    #pragma unroll
    for(int c=0;c<4;c++){
      short8 b0 = *(const short8*)&VT[(c*16+r_)*72 + qq*8];
      short8 b1 = *(const short8*)&VT[(c*16+r_)*72 + 32 + qq*8];
      pacc[c] = __builtin_amdgcn_mfma_f32_16x16x32_bf16(af0, b0, pacc[c], 0,0,0);
      pacc[c] = __builtin_amdgcn_mfma_f32_16x16x32_bf16(af1, b1, pacc[c], 0,0,0);
    }

    #pragma unroll
    for(int reg=0; reg<4; ++reg){
      int i = qt*64 + w*16 + qq*4 + reg;
      size_t base = (size_t)((h*TT + i)*8 + ct)*64;
      #pragma unroll
      for(int c=0;c<4;c++)
        part_acc[base + c*16 + r_] = bf16_rn(pacc[c][reg]);
    }
  }
}

// ============================================================================
// K3: merge <=8 bf16 chunk partials per (h,row) -> yF bf16 A-fragments.
// (unchanged)
// ============================================================================
__global__ void __launch_bounds__(256) attn_reduce(const unsigned short* __restrict__ part_acc,
    const float2* __restrict__ part_ml, unsigned short* __restrict__ yF){
  int wid  = (blockIdx.x * blockDim.x + threadIdx.x) >> 6;  // 0..6143
  int lane = threadIdx.x & 63;
  int h = wid >> 9;
  int i = wid & 511;
  int nch = (i >> 6) + 1;       // wave-uniform
  int base = (h*TT + i)*8;

  float2 mls[8]; float acs[8];
  #pragma unroll
  for(int c=0;c<8;c++){
    mls[c] = part_ml[base + c];
    acs[c] = bf16_to_f32(part_acc[(size_t)(base + c)*64 + lane]);
  }

  float m = -INFINITY, l = 0.f, a = 0.f;
  #pragma unroll
  for(int c=0;c<8;c++){
    if (c < nch){
      float m_new = fmaxf(m, mls[c].x);
      float sa  = __expf(m - m_new);
      float sc_ = __expf(mls[c].x - m_new);
      l = l*sa + mls[c].y*sc_;
      a = a*sa + acs[c]*sc_;
      m = m_new;
    }
  }
  float val = a / l;
  int s = i>>4, rr = i&15;
  int ks = h*2 + (lane>>5), q2 = (lane>>3)&3, j = lane&7;
  yF[ (((size_t)(s*24 + ks)*64 + q2*16 + rr)<<3) + j ] = bf16_rn(val);
}

// ============================================================================
// K4: proj GEMM, fragment-direct, 192 blocks (8mt x 24 ntH of 32 cols).
// 4-deep rotating register prefetch, fully unrolled (compile-time indices).
// (unchanged)
// ============================================================================
__global__ void __launch_bounds__(256) gemm_proj_mfma(
    const unsigned short* __restrict__ yF, const unsigned short* __restrict__ WpF,
    float* __restrict__ out){
  int bx = blockIdx.x;           // 0..191
  int mt = bx / 24, ntH = bx % 24;
  int tid = threadIdx.x, w = tid>>6, lane = tid&63, qq = lane>>4, r = lane&15;
  int s = mt*4 + w;   // 16-row strip

  const short8* Af = (const short8*)yF  + (size_t)s*24*64 + lane;
  const short8* Bf = (const short8*)WpF + lane;

  floatx4 acc[2];
  acc[0] = (floatx4){0.f,0.f,0.f,0.f};
  acc[1] = (floatx4){0.f,0.f,0.f,0.f};

  short8 ar[4]; short8 br[4][2];
  #pragma unroll
  for(int j=0;j<3;++j){
    ar[j] = Af[(size_t)j*64];
    #pragma unroll
    for(int c=0;c<2;c++) br[j][c] = Bf[(size_t)((ntH*2+c)*24 + j)*64];
  }

  #pragma unroll
  for(int ks=0; ks<24; ++ks){
    int cur = ks & 3;
    if (ks + 3 < 24){
      int nx = (ks+3) & 3;
      ar[nx] = Af[(size_t)(ks+3)*64];
      #pragma unroll
      for(int c=0;c<2;c++) br[nx][c] = Bf[(size_t)((ntH*2+c)*24 + ks+3)*64];
    }
    #pragma unroll
    for(int c=0;c<2;c++)
      acc[c] = __builtin_amdgcn_mfma_f32_16x16x32_bf16(ar[cur], br[cur][c], acc[c], 0,0,0);
  }

  #pragma unroll
  for(int reg=0; reg<4; ++reg){
    int t = mt*64 + w*16 + qq*4 + reg;
    float* dst = out + (size_t)t*CEMB + ntH*32;
    #pragma unroll
    for(int c=0;c<2;c++)
      dst[c*16 + r] = acc[c][reg];
  }
}

extern "C" void kernel_launch(void* const* d_in, const int* in_sizes, int n_in,
                              void* d_out, int out_size, void* d_ws, size_t ws_size,
                              hipStream_t stream){
  const float* x    = (const float*)d_in[0];
  const float* cosb = (const float*)d_in[1];
  const float* sinb = (const float*)d_in[2];
  const float* Wq   = (const float*)d_in[3];
  const float* Wk   = (const float*)d_in[4];
  const float* Wv   = (const float*)d_in[5];
  const float* Wp   = (const float*)d_in[6];
  float* out = (float*)d_out;

  float* ws        = (float*)d_ws;
  float* q_raw     = ws;                                // 512*768 f32
  float* k_raw     = q_raw + (size_t)TT*CEMB;           // 512*384 f32
  float* v_raw     = k_raw + (size_t)TT*KVC;            // 512*384 f32
  unsigned short* part_acc = (unsigned short*)(v_raw + (size_t)TT*KVC); // 12*512*8*64 bf16
  float2* part_ml  = (float2*)(part_acc + (size_t)NH*TT*8*64);          // 12*512*8
  unsigned short* WpF = (unsigned short*)(part_ml + (size_t)NH*TT*8);   // 48*24*64*8
  unsigned short* yF  = WpF + (size_t)48*24*64*8;       // 32*24*64*8

  gemm_qkv_mfma <<<dim3(228),   256, 0, stream>>>(x, Wq, Wk, Wv, Wp, cosb, sinb,
                                                  q_raw, k_raw, v_raw, WpF);
  attn_tile     <<<dim3(432),   256, 0, stream>>>(q_raw, k_raw, v_raw, part_acc, part_ml);
  attn_reduce   <<<dim3(NH*TT/4), 256, 0, stream>>>(part_acc, part_ml, yF);
  gemm_proj_mfma<<<dim3(192),   256, 0, stream>>>(yF, WpF, out);
}